// Round 1
// 169.582 us; speedup vs baseline: 1.0116x; 1.0116x over previous
//
#include <hip/hip_runtime.h>
#include <math.h>

typedef float f32x4 __attribute__((ext_vector_type(4)));
typedef __bf16 bf16x8 __attribute__((ext_vector_type(8)));

#define MFMA16(a, b, c) __builtin_amdgcn_mfma_f32_16x16x32_bf16((a), (b), (c), 0, 0, 0)

constexpr int Bsz = 2, Nseq = 2048, Dm = 1024, Hh = 16, HDim = 64, F3 = 192;
constexpr int Mrows = Bsz * Nseq;   // 4096
constexpr int NC = Hh * F3;         // 3072 output cols
constexpr float QSCALE = 0.125f * 1.4426950408889634f;

__device__ inline void load_lds16(const void* g, void* l) {
    __builtin_amdgcn_global_load_lds((const __attribute__((address_space(1))) void*)g,
                                     (__attribute__((address_space(3))) void*)l, 16, 0, 0);
}

// ---------------- kernel 0: x fp32 -> bf16 ----------------
__global__ __launch_bounds__(256) void conv_x_kernel(const float* __restrict__ x,
                                                     __bf16* __restrict__ xb) {
    int i = blockIdx.x * 256 + threadIdx.x;
    const float4* xv = reinterpret_cast<const float4*>(x);
    float4 a = xv[2 * i];
    float4 b = xv[2 * i + 1];
    bf16x8 o = {(__bf16)a.x, (__bf16)a.y, (__bf16)a.z, (__bf16)a.w,
                (__bf16)b.x, (__bf16)b.y, (__bf16)b.z, (__bf16)b.w};
    *reinterpret_cast<bf16x8*>(xb + 8 * i) = o;
}

// ---------------- kernel 1: W fp32 [h][d][c] -> bf16 transposed [h][c][d] ----------------
__global__ __launch_bounds__(256) void conv_w_kernel(const float* __restrict__ w,
                                                     __bf16* __restrict__ wt) {
    __shared__ __bf16 tile[32][66];
    int h = blockIdx.z, d0 = blockIdx.x * 32, c0 = blockIdx.y * 64;
    for (int i = threadIdx.x; i < 32 * 64; i += 256) {
        int di = i >> 6, cj = i & 63;
        tile[di][cj] = (__bf16)w[(size_t)(h * Dm + d0 + di) * F3 + c0 + cj];
    }
    __syncthreads();
    for (int i = threadIdx.x; i < 32 * 64; i += 256) {
        int ci = i >> 5, dj = i & 31;
        wt[(size_t)(h * F3 + c0 + ci) * Dm + d0 + dj] = tile[dj][ci];
    }
}

// ---------------- kernel 2a: proj as 256x256 deep-pipelined GEMM ----------------
// 8 waves (2M x 4N), per-wave output 128x64. BK=64, double-buffered LDS (128 KiB),
// counted vmcnt(8) (never 0 in main loop), stage of K-tile j+2 issued after the
// barrier that ends compute of K-tile j -> load-to-use distance = 1 full K-tile
// compute (~2000 cy), covering HBM latency. XCD-bijective block swizzle (192%8==0).
__global__ __launch_bounds__(512, 2) void gemm_proj(const __bf16* __restrict__ xb,
                                                    const __bf16* __restrict__ wt,
                                                    const float* __restrict__ bias,
                                                    __bf16* __restrict__ kbuf,
                                                    __bf16* __restrict__ qbuf,
                                                    __bf16* __restrict__ vt) {
    __shared__ __align__(16) __bf16 Ab[2][256 * 64];
    __shared__ __align__(16) __bf16 Bb[2][256 * 64];

    int flat = blockIdx.x;                       // 0..191
    int swz = (flat & 7) * 24 + (flat >> 3);     // bijective XCD swizzle (192 = 8*24)
    int bm = swz / 12, bn = swz % 12;            // 16 x 12 tile grid
    int r0 = bm * 256, n0 = bn * 256;

    int w = threadIdx.x >> 6, lane = threadIdx.x & 63;
    int col = lane & 15, quad = lane >> 4;
    int wm = w >> 2, wn = w & 3;

    f32x4 acc[8][4] = {};

    // stage K-tile kt (cols kt*64..) into LDS slot s. Per wave: rows w*32..w*32+31,
    // 4x (A,B) pairs of global_load_lds = 8 VMEM ops/wave/K-tile.
    // LDS[row][chunk] = global[row][chunk ^ (row&7)] (linear dest, pre-swizzled src).
    auto stage = [&](int kt, int s) {
        int rbase = w * 32;
        int rl = lane >> 3;
        int cg = ((lane & 7) ^ rl) * 8;          // row&7 == rl for all staged rows
#pragma unroll
        for (int i = 0; i < 4; i++) {
            int row = rbase + i * 8 + rl;
            load_lds16(xb + (size_t)(r0 + row) * Dm + kt * 64 + cg,
                       &Ab[s][(rbase + i * 8) * 64]);
            load_lds16(wt + (size_t)(n0 + row) * Dm + kt * 64 + cg,
                       &Bb[s][(rbase + i * 8) * 64]);
        }
    };

    stage(0, 0);
    stage(1, 1);

    for (int j = 0; j < 16; j++) {
        int s = j & 1;
        // counted wait: K-tile j landed; K-tile j+1 (8 loads) stays in flight
        if (j < 15) asm volatile("s_waitcnt vmcnt(8)" ::: "memory");
        else        asm volatile("s_waitcnt vmcnt(0)" ::: "memory");
        __builtin_amdgcn_s_barrier();
        asm volatile("" ::: "memory");

#pragma unroll
        for (int ks = 0; ks < 2; ks++) {
            int cq = ks * 4 + quad;
            bf16x8 af[8], bfr[4];
#pragma unroll
            for (int mt = 0; mt < 8; mt++) {
                int row = wm * 128 + mt * 16 + col;
                af[mt] = *reinterpret_cast<const bf16x8*>(
                    &Ab[s][row * 64 + ((cq ^ (row & 7)) * 8)]);
            }
#pragma unroll
            for (int nt = 0; nt < 4; nt++) {
                int row = wn * 64 + nt * 16 + col;
                bfr[nt] = *reinterpret_cast<const bf16x8*>(
                    &Bb[s][row * 64 + ((cq ^ (row & 7)) * 8)]);
            }
            __builtin_amdgcn_s_setprio(1);
#pragma unroll
            for (int mt = 0; mt < 8; mt++)
#pragma unroll
                for (int nt = 0; nt < 4; nt++)
                    acc[mt][nt] = MFMA16(af[mt], bfr[nt], acc[mt][nt]);
            __builtin_amdgcn_s_setprio(0);
        }

        asm volatile("" ::: "memory");
        __builtin_amdgcn_s_barrier();   // all waves done reading slot s
        asm volatile("" ::: "memory");
        if (j + 2 < 16) stage(j + 2, s);  // overwrite slot s for K-tile j+2
    }

#pragma unroll
    for (int nt = 0; nt < 4; nt++) {
        int g = n0 + wn * 64 + nt * 16 + col;
        int h = g / F3, c = g - h * F3;
        float bv = bias[g];
        bool isq = (c >= 64 && c < 128), isv = (c >= 128);
        int cd = c & 63;
#pragma unroll
        for (int mt = 0; mt < 8; mt++) {
#pragma unroll
            for (int rg = 0; rg < 4; rg++) {
                int r = r0 + wm * 128 + mt * 16 + quad * 4 + rg;
                int b = r >> 11, n = r & (Nseq - 1);
                float v = acc[mt][nt][rg] + bv;
                if (isq) v *= QSCALE;
                size_t bh = (size_t)(b * Hh + h);
                if (isv) vt[(bh * HDim + cd) * Nseq + n] = (__bf16)v;
                else ((isq) ? qbuf : kbuf)[(bh * Nseq + n) * HDim + cd] = (__bf16)v;
            }
        }
    }
}

// ---------------- kernel 2b: fallback proj if ws too small ----------------
__global__ __launch_bounds__(256) void proj_small(const float* __restrict__ x,
                                                  const __bf16* __restrict__ wt,
                                                  const float* __restrict__ bias,
                                                  __bf16* __restrict__ kbuf,
                                                  __bf16* __restrict__ qbuf,
                                                  __bf16* __restrict__ vt) {
    int h = blockIdx.y;
    int wave = threadIdx.x >> 6, lane = threadIdx.x & 63;
    int col = lane & 15, quad = lane >> 4;
    int r0 = blockIdx.x * 128 + wave * 32;

    f32x4 acc[12][2] = {};
    const float* xr0 = x + (size_t)(r0 + col) * Dm + quad * 8;
    const float* xr1 = xr0 + 16 * Dm;
    const __bf16* wbase = wt + (size_t)(h * F3 + col) * Dm + quad * 8;

    for (int k0 = 0; k0 < Dm; k0 += 32) {
        float4 a0lo = *reinterpret_cast<const float4*>(xr0 + k0);
        float4 a0hi = *reinterpret_cast<const float4*>(xr0 + k0 + 4);
        float4 a1lo = *reinterpret_cast<const float4*>(xr1 + k0);
        float4 a1hi = *reinterpret_cast<const float4*>(xr1 + k0 + 4);
        bf16x8 a0 = {(__bf16)a0lo.x, (__bf16)a0lo.y, (__bf16)a0lo.z, (__bf16)a0lo.w,
                     (__bf16)a0hi.x, (__bf16)a0hi.y, (__bf16)a0hi.z, (__bf16)a0hi.w};
        bf16x8 a1 = {(__bf16)a1lo.x, (__bf16)a1lo.y, (__bf16)a1lo.z, (__bf16)a1lo.w,
                     (__bf16)a1hi.x, (__bf16)a1hi.y, (__bf16)a1hi.z, (__bf16)a1hi.w};
#pragma unroll
        for (int ct = 0; ct < 12; ct++) {
            bf16x8 bf = *reinterpret_cast<const bf16x8*>(wbase + ct * 16 * Dm + k0);
            acc[ct][0] = MFMA16(a0, bf, acc[ct][0]);
            acc[ct][1] = MFMA16(a1, bf, acc[ct][1]);
        }
    }
#pragma unroll
    for (int ct = 0; ct < 12; ct++) {
        int c = ct * 16 + col;
        float bv = bias[h * F3 + c];
        int cd = c & 63;
        bool isq = (c >= 64 && c < 128), isv = (c >= 128);
#pragma unroll
        for (int rt = 0; rt < 2; rt++) {
#pragma unroll
            for (int rg = 0; rg < 4; rg++) {
                int r = r0 + rt * 16 + quad * 4 + rg;
                int b = r >> 11, n = r & (Nseq - 1);
                float v = acc[ct][rt][rg] + bv;
                if (isq) v *= QSCALE;
                size_t bh = (size_t)(b * Hh + h);
                if (isv) vt[(bh * HDim + cd) * Nseq + n] = (__bf16)v;
                else ((isq) ? qbuf : kbuf)[(bh * Nseq + n) * HDim + cd] = (__bf16)v;
            }
        }
    }
}

// ---------------- kernel 3: flash attention with LDS-staged K/V tiles ----------------
__global__ __launch_bounds__(512) void attn_kernel(const __bf16* __restrict__ qbuf,
                                                   const __bf16* __restrict__ kbuf,
                                                   const __bf16* __restrict__ vt,
                                                   float* __restrict__ out) {
    __shared__ __align__(16) __bf16 Kb[64 * 64];       // [key][dim], swizzled chunks
    __shared__ __align__(16) __bf16 Vb[64 * 64];       // [dim][key], swizzled chunks
    __shared__ __align__(16) __bf16 plds[8][16][72];   // per-wave P tile, 2-way max
    int bh = blockIdx.x;
    int b = bh >> 4, h = bh & 15;
    int pair = blockIdx.y;
    int wave = threadIdx.x >> 6, lane = threadIdx.x & 63;
    int col = lane & 15, quad = lane >> 4;
    int tile = (wave < 4) ? pair : (31 - pair);
    int q0 = tile * 64 + (wave & 3) * 16;

    const __bf16* qbase = qbuf + (size_t)bh * Nseq * HDim;
    const __bf16* kbase = kbuf + (size_t)bh * Nseq * HDim;
    const __bf16* vbase = vt + (size_t)bh * HDim * Nseq;

    bf16x8 aq0 = *reinterpret_cast<const bf16x8*>(qbase + (q0 + col) * HDim + quad * 8);
    bf16x8 aq1 = *reinterpret_cast<const bf16x8*>(qbase + (q0 + col) * HDim + quad * 8 + 32);

    f32x4 o[4] = {};
    float lsum[4] = {0.f, 0.f, 0.f, 0.f};

    int mb = q0 & ~63;                  // the one masked 64-key block for this wave
    int loop_end = 2048 - 64 * pair;    // max kend over both tiles, rounded to 64

    // staging indices (thread-invariant across iterations)
    int srow = threadIdx.x >> 3;                      // key (K) / dim (V) row 0..63
    int schunk = (threadIdx.x & 7) ^ (srow & 7);      // swizzled 16B chunk
    const __bf16* ksrc0 = kbase + srow * HDim + schunk * 8;
    const __bf16* vsrc0 = vbase + (size_t)srow * Nseq + schunk * 8;
    __bf16* kdst = Kb + wave * 512;
    __bf16* vdst = Vb + wave * 512;

    // readback swizzle offsets
    int sw0 = ((quad ^ (col & 7)) * 8);
    int sw1 = (((quad + 4) ^ (col & 7)) * 8);

    for (int kb = 0; kb < loop_end; kb += 64) {
        __syncthreads();  // previous iteration's LDS reads complete
        load_lds16(ksrc0 + kb * HDim, kdst);
        load_lds16(vsrc0 + kb, vdst);
        __syncthreads();  // staging visible

        if (kb <= mb) {
            bool masked = (kb == mb);
            // QK^T from LDS K tile
            f32x4 z = {};
            f32x4 s[4];
#pragma unroll
            for (int g = 0; g < 4; g++) {
                const __bf16* krow = Kb + (col + 16 * g) * 64;
                bf16x8 k0 = *reinterpret_cast<const bf16x8*>(krow + sw0);
                bf16x8 k1 = *reinterpret_cast<const bf16x8*>(krow + sw1);
                s[g] = MFMA16(aq0, k0, z);
                s[g] = MFMA16(aq1, k1, s[g]);
            }
            // softmax (no-max) + P to LDS
            if (masked) {
#pragma unroll
                for (int g = 0; g < 4; g++) {
#pragma unroll
                    for (int r = 0; r < 4; r++) {
                        int qi = q0 + quad * 4 + r;
                        float p = (kb + col + 16 * g <= qi) ? exp2f(s[g][r]) : 0.f;
                        lsum[r] += p;
                        plds[wave][quad * 4 + r][col + 16 * g] = (__bf16)p;
                    }
                }
            } else {
#pragma unroll
                for (int g = 0; g < 4; g++) {
#pragma unroll
                    for (int r = 0; r < 4; r++) {
                        float p = exp2f(s[g][r]);
                        lsum[r] += p;
                        plds[wave][quad * 4 + r][col + 16 * g] = (__bf16)p;
                    }
                }
            }
            bf16x8 pa0 = *reinterpret_cast<const bf16x8*>(&plds[wave][col][quad * 8]);
            bf16x8 pa1 = *reinterpret_cast<const bf16x8*>(&plds[wave][col][32 + quad * 8]);
            // PV from LDS V tile
#pragma unroll
            for (int nt = 0; nt < 4; nt++) {
                const __bf16* vrow = Vb + (col + 16 * nt) * 64;
                bf16x8 v0 = *reinterpret_cast<const bf16x8*>(vrow + sw0);
                bf16x8 v1 = *reinterpret_cast<const bf16x8*>(vrow + sw1);
                o[nt] = MFMA16(pa0, v0, o[nt]);
                o[nt] = MFMA16(pa1, v1, o[nt]);
            }
        }
    }

    float linv[4];
#pragma unroll
    for (int r = 0; r < 4; r++) {
        float s = lsum[r];
        s += __shfl_xor(s, 1);
        s += __shfl_xor(s, 2);
        s += __shfl_xor(s, 4);
        s += __shfl_xor(s, 8);
        linv[r] = 1.f / s;
    }
#pragma unroll
    for (int nt = 0; nt < 4; nt++) {
#pragma unroll
        for (int r = 0; r < 4; r++) {
            int qi = q0 + quad * 4 + r;
            out[((size_t)(b * Nseq + qi)) * Dm + h * HDim + nt * 16 + col] = o[nt][r] * linv[r];
        }
    }
}

extern "C" void kernel_launch(void* const* d_in, const int* in_sizes, int n_in,
                              void* d_out, int out_size, void* d_ws, size_t ws_size,
                              hipStream_t stream) {
    const float* x = nullptr;
    const float* w = nullptr;
    const float* bias = nullptr;
    for (int i = 0; i < n_in; i++) {
        if (in_sizes[i] == Mrows * Dm) x = (const float*)d_in[i];
        else if (in_sizes[i] == Hh * Dm * F3) w = (const float*)d_in[i];
        else if (in_sizes[i] == Hh * F3) bias = (const float*)d_in[i];
    }
    float* outp = (float*)d_out;

    // ws: wt 6 MB | kbuf 8 | qbuf 8 | vt 8 | xb 8 -> 38 MB
    char* ws = (char*)d_ws;
    __bf16* wt = (__bf16*)(ws);
    __bf16* kbuf = (__bf16*)(ws + 6291456);
    __bf16* qbuf = (__bf16*)(ws + 6291456 + 8388608);
    __bf16* vt = (__bf16*)(ws + 6291456 + 2 * 8388608);
    __bf16* xb = (__bf16*)(ws + 6291456 + 3 * 8388608);

    conv_w_kernel<<<dim3(Dm / 32, F3 / 64, Hh), 256, 0, stream>>>(w, wt);
    if (ws_size >= (size_t)(6291456 + 4 * 8388608)) {
        conv_x_kernel<<<Mrows * Dm / (8 * 256), 256, 0, stream>>>(x, xb);
        gemm_proj<<<dim3(Mrows / 256 * (NC / 256)), 512, 0, stream>>>(xb, wt, bias, kbuf, qbuf, vt);
    } else {
        proj_small<<<dim3(Mrows / 128, Hh), 256, 0, stream>>>(x, wt, bias, kbuf, qbuf, vt);
    }
    attn_kernel<<<dim3(32, 16), 512, 0, stream>>>(qbuf, kbuf, vt, outp);
}